// Round 10
// baseline (117.869 us; speedup 1.0000x reference)
//
#include <hip/hip_runtime.h>

#define EPSF 1e-9f

typedef float v2f __attribute__((ext_vector_type(2)));

constexpr int I   = 144;    // 9*16 input capsules
constexpr int IC  = 36;     // i's per chunk (4 chunks per wave)
constexpr int RT  = 148;    // s_zr row stride (144 + 4 pad)
constexpr int SP  = 20;     // s_pose row stride (16 + 4 pad)
constexpr int QS  = 68;     // s_q row stride (64 + 4 pad, 16B-aligned)

// Intra-quad reductions on the VALU pipe (DPP quad_perm), NOT the DS pipe.
// 0xB1 = quad_perm [1,0,3,2] (xor 1), 0x4E = quad_perm [2,3,0,1] (xor 2).
__device__ __forceinline__ float quad_sum(float x) {
    int a = __builtin_amdgcn_update_dpp(0, __float_as_int(x), 0xB1, 0xF, 0xF, true);
    float y = x + __int_as_float(a);
    int b = __builtin_amdgcn_update_dpp(0, __float_as_int(y), 0x4E, 0xF, 0xF, true);
    return y + __int_as_float(b);
}
__device__ __forceinline__ float quad_max(float x) {
    int a = __builtin_amdgcn_update_dpp(0, __float_as_int(x), 0xB1, 0xF, 0xF, true);
    float y = fmaxf(x, __int_as_float(a));
    int b = __builtin_amdgcn_update_dpp(0, __float_as_int(y), 0x4E, 0xF, 0xF, true);
    return fmaxf(y, __int_as_float(b));
}
// Fast 1/x (v_rcp_f32, ~1 ulp): fine under the 2e-2 absmax threshold.
__device__ __forceinline__ float frcp(float x) { return __builtin_amdgcn_rcpf(x); }

// wt[i,o,pc,q] = w[i,o,q,pc]  -> vote loop reads one float4 per (i, lane)
__global__ void transpose_w_kernel(const float* __restrict__ w, float* __restrict__ wt) {
    const int i = blockIdx.x;
    const int t = threadIdx.x;                  // t = o*16 + q*4 + pc
    const float val = w[i * 256 + t];
    const int o = t >> 4, q = (t >> 2) & 3, pc = t & 3;
    wt[i * 256 + o * 16 + pc * 4 + q] = val;
}

// Block = 1024 = 16 waves; wave = one o. lane = c*16 + p (c = i-chunk, p = pose elem).
// M-step reductions fully in-wave (shfl 16/32 chunks, DPP quads for p).
// Votes stored as v2f pairs -> M/E inner loops use v_pk_{fma,add,mul}_f32.
// Vote loop stays SCALAR, writing .x/.y slots (no transpose movs — R7 lesson).
// E-step: quad sum over pc on VALU (DPP, scalar); 9 unmasked ds_write_b32/thread.
// NOTE (R7): packing with transposed build-vectors REGRESSED 65->72.6 us
// (v_mov shuffles lengthen chains). Pack only register-free pairs.
// NOTE (R8): '#pragma unroll' on the 3-iter EM loop REGRESSED (3x hot-body
// code size -> I-fetch stalls). Keep the loop ROLLED (unroll 1).
// launch_bounds (1024,4): 128-VGPR cap. (1024,8) capped at 32 VGPR in R3 and
// spilled the vote array -> 394 MB scratch traffic. Do not tighten.
template <bool USE_WT>
__global__ __launch_bounds__(1024, 4)
void capsule_em_kernel(const float* __restrict__ pose_in,   // [8,14,14,256]
                       const float* __restrict__ act_in,    // [8,14,14,16]
                       const float* __restrict__ wmat,      // wt (transposed) or w
                       const float* __restrict__ beta_v,    // [16]
                       const float* __restrict__ beta_a,    // [16]
                       float* __restrict__ out)             // pose 294912 | act 18432
{
    __shared__ __align__(16) float s_pose[I * SP];   // 11520 B
    __shared__ __align__(16) float s_zr[16 * RT];    //  9472 B  rr' [o][i]
    __shared__ __align__(16) float s_q[I * QS];      // 39168 B  q partials [i][o*4+pr]
    __shared__ __align__(16) float s_iact[I + 4];    //   592 B
    __shared__ float s_Lo[16];                       //    64 B

    const int tid  = threadIdx.x;
    const int o    = tid >> 6;          // wave id
    const int lane = tid & 63;
    const int c    = lane >> 4;
    const int p    = lane & 15;
    const int pr   = p >> 2;
    const int pc   = p & 3;
    const int i0   = c * IC;

    const int n   = blockIdx.x;
    const int b   = n / 144;
    const int rem = n - b * 144;
    const int hp  = rem / 12;
    const int wp  = rem - hp * 12;

    // ---- stage pose patch (9 x 256 floats, float4) + i_act ----
    if (tid < 576) {
        const int pk = tid >> 6, l6 = tid & 63;
        const int ki = pk / 3, kj = pk - ki * 3;
        const float4 val = *reinterpret_cast<const float4*>(
            &pose_in[((b * 14 + hp + ki) * 14 + (wp + kj)) * 256 + l6 * 4]);
        const int i = pk * 16 + (l6 >> 2), e = (l6 & 3) * 4;
        *reinterpret_cast<float4*>(&s_pose[i * SP + e]) = val;
    } else if (tid < 720) {
        const int t = tid - 576;
        const int pk = t >> 4, ic = t & 15;
        const int ki = pk / 3, kj = pk - ki * 3;
        s_iact[t] = act_in[((b * 14 + hp + ki) * 14 + (wp + kj)) * 16 + ic];
    }
    __syncthreads();

    // ---- votes (scalar compute, paired storage): v2[m] = {vote 2m, vote 2m+1} ----
    v2f v2[IC / 2];
    #pragma unroll
    for (int m = 0; m < IC / 2; ++m) {
        float pair[2];
        #pragma unroll
        for (int h = 0; h < 2; ++h) {
            const int i = i0 + 2 * m + h;
            const float4 pv = *reinterpret_cast<const float4*>(&s_pose[i * SP + pr * 4]);
            if (USE_WT) {
                const float4 wv = *reinterpret_cast<const float4*>(&wmat[i * 256 + o * 16 + pc * 4]);
                pair[h] = pv.x * wv.x + pv.y * wv.y + pv.z * wv.z + pv.w * wv.w;
            } else {
                const float* wb = &wmat[i * 256 + o * 16 + pc];
                pair[h] = pv.x * wb[0] + pv.y * wb[4] + pv.z * wb[8] + pv.w * wb[12];
            }
        }
        v2[m] = (v2f){pair[0], pair[1]};
    }

    const float bv = beta_v[o];
    const float ba = beta_a[o];

    float mean = 0.0f, o_act = 0.0f;

    #pragma unroll 1
    for (int it = 0; it < 3; ++it) {
        // ---------------- M-step (wave-autonomous, no barriers; packed) --------
        v2f aS = (v2f)0.0f, a1 = (v2f)0.0f, a2 = (v2f)0.0f;
        const float* rrow = (it == 0) ? &s_iact[i0] : &s_zr[o * RT + i0];
        #pragma unroll
        for (int jj = 0; jj < 9; ++jj) {
            const float4 r4 = *reinterpret_cast<const float4*>(&rrow[jj * 4]);
            const v2f ra = (v2f){r4.x, r4.y};   // subregister views of r4 (free)
            const v2f rb = (v2f){r4.z, r4.w};
            const v2f va = v2[2 * jj], vb = v2[2 * jj + 1];
            aS += ra;              aS += rb;            // pk_add
            const v2f ta = ra * va, tb = rb * vb;       // pk_mul
            a1 += ta;              a1 += tb;            // pk_add
            a2 += ta * va;         a2 += tb * vb;       // pk_fma
        }
        float accS = aS.x + aS.y;
        float acc1 = a1.x + a1.y;
        float acc2 = a2.x + a2.y;
        accS += __shfl_xor(accS, 16); accS += __shfl_xor(accS, 32);
        acc1 += __shfl_xor(acc1, 16); acc1 += __shfl_xor(acc1, 32);
        acc2 += __shfl_xor(acc2, 16); acc2 += __shfl_xor(acc2, 32);
        if (it == 0) {   // iter-0 rr' = iact/16: fold 1/16 after reduction
            accS *= 0.0625f; acc1 *= 0.0625f; acc2 *= 0.0625f;
        }

        const float inv = frcp(accS + EPSF);
        mean = acc1 * inv;
        float var = (acc2 - 2.0f * mean * acc1 + mean * mean * accS) * inv;
        var = fmaxf(var, 0.0f);
        // log(sigma+1e-9) == 0.5*log(var+1e-18) (exact in both limits) -> no sqrt
        float slog = quad_sum(0.5f * __logf(var + 1e-18f));   // masks 1,2 on VALU
        slog += __shfl_xor(slog, 4);                          // masks 4,8 on DS
        slog += __shfl_xor(slog, 8);

        const float cost_sum = accS * (16.0f * bv + slog);
        const float inv_temp = 1.0f + (float)it;
        o_act = frcp(1.0f + __expf(-inv_temp * (ba - cost_sum)));

        // ---------------- E-step (skip on last iter) ----------------
        if (it < 2) {
            // d^2*a = v*(v*a - 2*mean*a) + mean^2*a; the mean^2*a term is
            // vote-independent -> full p-sum once, folded into Lo.
            const float a  = frcp(2.0f * var + EPSF);
            const float b2 = 2.0f * mean * a;
            float cq = quad_sum(mean * mean * a);
            cq += __shfl_xor(cq, 4);
            cq += __shfl_xor(cq, 8);
            const float Lo = __logf(o_act + EPSF) - slog - cq;
            if (lane == 0) s_Lo[o] = Lo;
            const v2f av2  = (v2f){a, a};
            const v2f nb22 = (v2f){-b2, -b2};
            #pragma unroll
            for (int j = 0; j < 9; ++j) {
                const v2f vA = v2[2 * j], vB = v2[2 * j + 1];
                const v2f s1A = vA * av2 + nb22;   // pk_fma: v*a - 2*mean*a
                const v2f s1B = vB * av2 + nb22;
                const v2f qA = vA * s1A;           // pk_mul
                const v2f qB = vB * s1B;
                float qs[4];
                qs[0] = quad_sum(qA.x);            // sum over pc (scalar DPP)
                qs[1] = quad_sum(qA.y);
                qs[2] = quad_sum(qB.x);
                qs[3] = quad_sum(qB.y);
                float val = qs[0];
                val = (pc == 1) ? qs[1] : val;
                val = (pc == 2) ? qs[2] : val;
                val = (pc == 3) ? qs[3] : val;
                // lane (c,pr,pc) writes vote i0+4j+pc's pr-partial: unmasked b32
                s_q[(i0 + 4 * j + pc) * QS + o * 4 + pr] = val;
            }
            __syncthreads();
            // softmax over o per i: 576 threads, 4 o's each (quad ladders on VALU)
            if (tid < 576) {
                const int si = tid >> 2, sj = tid & 3;
                float zz[4];
                #pragma unroll
                for (int k = 0; k < 4; ++k) {
                    const float4 qv = *reinterpret_cast<const float4*>(
                        &s_q[si * QS + (sj * 4 + k) * 4]);
                    zz[k] = s_Lo[sj * 4 + k] - (qv.x + qv.y + qv.z + qv.w);
                }
                float m = fmaxf(fmaxf(zz[0], zz[1]), fmaxf(zz[2], zz[3]));
                m = quad_max(m);
                const float e0 = __expf(zz[0] - m), e1 = __expf(zz[1] - m);
                const float e2 = __expf(zz[2] - m), e3 = __expf(zz[3] - m);
                const float s = quad_sum(e0 + e1 + e2 + e3);
                const float sc = s_iact[si] * frcp(s);    // fold i_act into rr'
                s_zr[(sj * 4 + 0) * RT + si] = e0 * sc;
                s_zr[(sj * 4 + 1) * RT + si] = e1 * sc;
                s_zr[(sj * 4 + 2) * RT + si] = e2 * sc;
                s_zr[(sj * 4 + 3) * RT + si] = e3 * sc;
            }
            __syncthreads();
        }
    }

    // ---- outputs ----
    if (c == 0) out[n * 256 + o * 16 + p] = mean;                // pose
    if (lane == 0) out[8 * 12 * 12 * 256 + n * 16 + o] = o_act;  // activation
}

extern "C" void kernel_launch(void* const* d_in, const int* in_sizes, int n_in,
                              void* d_out, int out_size, void* d_ws, size_t ws_size,
                              hipStream_t stream) {
    const float* pose = (const float*)d_in[0];
    const float* act  = (const float*)d_in[1];
    const float* w    = (const float*)d_in[2];
    const float* bv   = (const float*)d_in[3];
    const float* ba   = (const float*)d_in[4];
    float* out = (float*)d_out;

    const size_t wt_bytes = size_t(I) * 256 * sizeof(float);   // 147456
    if (ws_size >= wt_bytes) {
        float* wt = (float*)d_ws;
        transpose_w_kernel<<<dim3(I), dim3(256), 0, stream>>>(w, wt);
        capsule_em_kernel<true><<<dim3(1152), dim3(1024), 0, stream>>>(pose, act, wt, bv, ba, out);
    } else {
        capsule_em_kernel<false><<<dim3(1152), dim3(1024), 0, stream>>>(pose, act, w, bv, ba, out);
    }
}

// Round 11
// 114.864 us; speedup vs baseline: 1.0262x; 1.0262x over previous
//
#include <hip/hip_runtime.h>

#define EPSF 1e-9f

constexpr int I   = 144;    // 9*16 input capsules
constexpr int IC  = 36;     // i's per chunk (4 chunks per wave)
constexpr int RT  = 148;    // s_zr row stride (144 + 4 pad)
constexpr int SP  = 20;     // s_pose row stride (16 + 4 pad)
constexpr int QS  = 68;     // s_q row stride (64 + 4 pad, 16B-aligned)

// Intra-quad reductions on the VALU pipe (DPP quad_perm), NOT the DS pipe.
// 0xB1 = quad_perm [1,0,3,2] (xor 1), 0x4E = quad_perm [2,3,0,1] (xor 2).
// 0x124 = row_ror:4, 0x128 = row_ror:8 (rows are 16 lanes on gfx9/CDNA).
__device__ __forceinline__ float quad_sum(float x) {
    int a = __builtin_amdgcn_update_dpp(0, __float_as_int(x), 0xB1, 0xF, 0xF, true);
    float y = x + __int_as_float(a);
    int b = __builtin_amdgcn_update_dpp(0, __float_as_int(y), 0x4E, 0xF, 0xF, true);
    return y + __int_as_float(b);
}
__device__ __forceinline__ float quad_max(float x) {
    int a = __builtin_amdgcn_update_dpp(0, __float_as_int(x), 0xB1, 0xF, 0xF, true);
    float y = fmaxf(x, __int_as_float(a));
    int b = __builtin_amdgcn_update_dpp(0, __float_as_int(y), 0x4E, 0xF, 0xF, true);
    return fmaxf(y, __int_as_float(b));
}
// Full sum across the 16-lane row (= all p for fixed chunk), entirely on VALU:
// quad ladder leaves [AAAA BBBB CCCC DDDD]; +ror4 then +ror8 -> total in all lanes.
__device__ __forceinline__ float row_sum16(float x) {
    float y = quad_sum(x);
    int a = __builtin_amdgcn_update_dpp(0, __float_as_int(y), 0x124, 0xF, 0xF, true);
    y += __int_as_float(a);
    a = __builtin_amdgcn_update_dpp(0, __float_as_int(y), 0x128, 0xF, 0xF, true);
    return y + __int_as_float(a);
}
// Fast 1/x (v_rcp_f32, ~1 ulp): fine under the 2e-2 absmax threshold.
__device__ __forceinline__ float frcp(float x) { return __builtin_amdgcn_rcpf(x); }

// wt[i,o,pc,q] = w[i,o,q,pc]  -> vote loop reads one float4 per (i, lane)
__global__ void transpose_w_kernel(const float* __restrict__ w, float* __restrict__ wt) {
    const int i = blockIdx.x;
    const int t = threadIdx.x;                  // t = o*16 + q*4 + pc
    const float val = w[i * 256 + t];
    const int o = t >> 4, q = (t >> 2) & 3, pc = t & 3;
    wt[i * 256 + o * 16 + pc * 4 + q] = val;
}

// Block = 1024 = 16 waves; wave = one o. lane = c*16 + p (c = i-chunk, p = pose elem).
// M-step reductions fully in-wave (shfl 16/32 chunks, DPP row_sum16 for p).
// E-step: quad sum over pc on VALU (DPP); 9 unmasked ds_write_b32 per thread.
// NOTE (R7/R10): fp32 pk-packing is neutral-to-negative here (build-vector movs
// or no dur gain despite lower busy). Keep scalar + DPP.
// NOTE (R8): '#pragma unroll' on the 3-iter EM loop REGRESSED (3x hot-body
// code size -> I-fetch stalls). Keep the loop ROLLED (unroll 1).
// NOTE (R11): slog/cq p-sums use row_ror DPP (VALU) instead of shfl_xor 4/8
// (DS) — the epilogue is a full-wave serial chain; DS shuffle latency there
// is pure stall.
// launch_bounds (1024,4): 128-VGPR cap. (1024,8) capped at 32 VGPR in R3 and
// spilled the vote array -> 394 MB scratch traffic. Do not tighten.
template <bool USE_WT>
__global__ __launch_bounds__(1024, 4)
void capsule_em_kernel(const float* __restrict__ pose_in,   // [8,14,14,256]
                       const float* __restrict__ act_in,    // [8,14,14,16]
                       const float* __restrict__ wmat,      // wt (transposed) or w
                       const float* __restrict__ beta_v,    // [16]
                       const float* __restrict__ beta_a,    // [16]
                       float* __restrict__ out)             // pose 294912 | act 18432
{
    __shared__ __align__(16) float s_pose[I * SP];   // 11520 B
    __shared__ __align__(16) float s_zr[16 * RT];    //  9472 B  rr' [o][i]
    __shared__ __align__(16) float s_q[I * QS];      // 39168 B  q partials [i][o*4+pr]
    __shared__ __align__(16) float s_iact[I + 4];    //   592 B
    __shared__ float s_Lo[16];                       //    64 B

    const int tid  = threadIdx.x;
    const int o    = tid >> 6;          // wave id
    const int lane = tid & 63;
    const int c    = lane >> 4;
    const int p    = lane & 15;
    const int pr   = p >> 2;
    const int pc   = p & 3;
    const int i0   = c * IC;

    const int n   = blockIdx.x;
    const int b   = n / 144;
    const int rem = n - b * 144;
    const int hp  = rem / 12;
    const int wp  = rem - hp * 12;

    // ---- stage pose patch (9 x 256 floats, float4) + i_act ----
    if (tid < 576) {
        const int pk = tid >> 6, l6 = tid & 63;
        const int ki = pk / 3, kj = pk - ki * 3;
        const float4 val = *reinterpret_cast<const float4*>(
            &pose_in[((b * 14 + hp + ki) * 14 + (wp + kj)) * 256 + l6 * 4]);
        const int i = pk * 16 + (l6 >> 2), e = (l6 & 3) * 4;
        *reinterpret_cast<float4*>(&s_pose[i * SP + e]) = val;
    } else if (tid < 720) {
        const int t = tid - 576;
        const int pk = t >> 4, ic = t & 15;
        const int ki = pk / 3, kj = pk - ki * 3;
        s_iact[t] = act_in[((b * 14 + hp + ki) * 14 + (wp + kj)) * 16 + ic];
    }
    __syncthreads();

    // ---- votes: v[ii] = sum_q pose[i,pr,q] * w[i,o,q,pc], i = i0+ii ----
    float v[IC];
    #pragma unroll
    for (int ii = 0; ii < IC; ++ii) {
        const int i = i0 + ii;
        const float4 pv = *reinterpret_cast<const float4*>(&s_pose[i * SP + pr * 4]);
        if (USE_WT) {
            const float4 wv = *reinterpret_cast<const float4*>(&wmat[i * 256 + o * 16 + pc * 4]);
            v[ii] = pv.x * wv.x + pv.y * wv.y + pv.z * wv.z + pv.w * wv.w;
        } else {
            const float* wb = &wmat[i * 256 + o * 16 + pc];
            v[ii] = pv.x * wb[0] + pv.y * wb[4] + pv.z * wb[8] + pv.w * wb[12];
        }
    }

    const float bv = beta_v[o];
    const float ba = beta_a[o];

    float mean = 0.0f, o_act = 0.0f;

    #pragma unroll 1
    for (int it = 0; it < 3; ++it) {
        // ---------------- M-step (wave-autonomous, no barriers) ----------------
        float accS = 0.0f, acc1 = 0.0f, acc2 = 0.0f;
        const float* rrow = (it == 0) ? &s_iact[i0] : &s_zr[o * RT + i0];
        #pragma unroll
        for (int jj = 0; jj < 9; ++jj) {
            const float4 r4 = *reinterpret_cast<const float4*>(&rrow[jj * 4]);
            const float r[4] = {r4.x, r4.y, r4.z, r4.w};
            #pragma unroll
            for (int k = 0; k < 4; ++k) {
                const float t = r[k] * v[jj * 4 + k];
                accS += r[k];
                acc1 += t;
                acc2 += t * v[jj * 4 + k];
            }
        }
        accS += __shfl_xor(accS, 16); accS += __shfl_xor(accS, 32);
        acc1 += __shfl_xor(acc1, 16); acc1 += __shfl_xor(acc1, 32);
        acc2 += __shfl_xor(acc2, 16); acc2 += __shfl_xor(acc2, 32);
        if (it == 0) {   // iter-0 rr' = iact/16: fold 1/16 after reduction
            accS *= 0.0625f; acc1 *= 0.0625f; acc2 *= 0.0625f;
        }

        const float inv = frcp(accS + EPSF);
        mean = acc1 * inv;
        float var = (acc2 - 2.0f * mean * acc1 + mean * mean * accS) * inv;
        var = fmaxf(var, 0.0f);
        // log(sigma+1e-9) == 0.5*log(var+1e-18) (exact in both limits) -> no sqrt
        const float slog = row_sum16(0.5f * __logf(var + 1e-18f));  // all on VALU

        const float cost_sum = accS * (16.0f * bv + slog);
        const float inv_temp = 1.0f + (float)it;
        o_act = frcp(1.0f + __expf(-inv_temp * (ba - cost_sum)));

        // ---------------- E-step (skip on last iter) ----------------
        if (it < 2) {
            // d^2*a = v*(v*a - 2*mean*a) + mean^2*a; the mean^2*a term is
            // vote-independent -> full p-sum once (VALU), folded into Lo.
            const float a  = frcp(2.0f * var + EPSF);
            const float b2 = 2.0f * mean * a;
            const float cq = row_sum16(mean * mean * a);
            const float Lo = __logf(o_act + EPSF) - slog - cq;
            if (lane == 0) s_Lo[o] = Lo;
            #pragma unroll
            for (int j = 0; j < 9; ++j) {
                float qs[4];
                #pragma unroll
                for (int t = 0; t < 4; ++t) {
                    const float vv = v[4 * j + t];
                    const float s1 = fmaf(vv, a, -b2);        // v*a - 2*mean*a
                    qs[t] = quad_sum(vv * s1);                // sum over pc
                }
                float val = qs[0];
                val = (pc == 1) ? qs[1] : val;
                val = (pc == 2) ? qs[2] : val;
                val = (pc == 3) ? qs[3] : val;
                // lane (c,pr,pc) writes vote i0+4j+pc's pr-partial: unmasked b32
                s_q[(i0 + 4 * j + pc) * QS + o * 4 + pr] = val;
            }
            __syncthreads();
            // softmax over o per i: 576 threads, 4 o's each (quad ladders on VALU)
            if (tid < 576) {
                const int si = tid >> 2, sj = tid & 3;
                float zz[4];
                #pragma unroll
                for (int k = 0; k < 4; ++k) {
                    const float4 qv = *reinterpret_cast<const float4*>(
                        &s_q[si * QS + (sj * 4 + k) * 4]);
                    zz[k] = s_Lo[sj * 4 + k] - (qv.x + qv.y + qv.z + qv.w);
                }
                float m = fmaxf(fmaxf(zz[0], zz[1]), fmaxf(zz[2], zz[3]));
                m = quad_max(m);
                const float e0 = __expf(zz[0] - m), e1 = __expf(zz[1] - m);
                const float e2 = __expf(zz[2] - m), e3 = __expf(zz[3] - m);
                const float s = quad_sum(e0 + e1 + e2 + e3);
                const float sc = s_iact[si] * frcp(s);    // fold i_act into rr'
                s_zr[(sj * 4 + 0) * RT + si] = e0 * sc;
                s_zr[(sj * 4 + 1) * RT + si] = e1 * sc;
                s_zr[(sj * 4 + 2) * RT + si] = e2 * sc;
                s_zr[(sj * 4 + 3) * RT + si] = e3 * sc;
            }
            __syncthreads();
        }
    }

    // ---- outputs ----
    if (c == 0) out[n * 256 + o * 16 + p] = mean;                // pose
    if (lane == 0) out[8 * 12 * 12 * 256 + n * 16 + o] = o_act;  // activation
}

extern "C" void kernel_launch(void* const* d_in, const int* in_sizes, int n_in,
                              void* d_out, int out_size, void* d_ws, size_t ws_size,
                              hipStream_t stream) {
    const float* pose = (const float*)d_in[0];
    const float* act  = (const float*)d_in[1];
    const float* w    = (const float*)d_in[2];
    const float* bv   = (const float*)d_in[3];
    const float* ba   = (const float*)d_in[4];
    float* out = (float*)d_out;

    const size_t wt_bytes = size_t(I) * 256 * sizeof(float);   // 147456
    if (ws_size >= wt_bytes) {
        float* wt = (float*)d_ws;
        transpose_w_kernel<<<dim3(I), dim3(256), 0, stream>>>(w, wt);
        capsule_em_kernel<true><<<dim3(1152), dim3(1024), 0, stream>>>(pose, act, wt, bv, ba, out);
    } else {
        capsule_em_kernel<false><<<dim3(1152), dim3(1024), 0, stream>>>(pose, act, w, bv, ba, out);
    }
}